// Round 15
// baseline (81.009 us; speedup 1.0000x reference)
//
#include <hip/hip_runtime.h>
#include <hip/hip_bf16.h>
#include <math.h>

#define NN 4096
#define BB 8
#define CC 128
#define EE 131072
#define M_ROWS (BB*NN)      // 32768
#define DEG_CAP 128

typedef __attribute__((ext_vector_type(8))) short short8;
typedef __attribute__((ext_vector_type(4))) float f32x4;

__device__ __forceinline__ float bf2f(unsigned int u){
    union { unsigned int i; float f; } v; v.i = u << 16; return v.f;
}
__device__ __forceinline__ unsigned short f2bf(float f){
    union { float f; unsigned int i; } v; v.f = f;
    unsigned int u = v.i;
    unsigned int r = u + 0x7FFFu + ((u >> 16) & 1u);
    return (unsigned short)(r >> 16);
}

// swizzled byte offset for element (row r, k) in a [rows][128] bf16 LDS tile (256B rows)
__device__ __forceinline__ int swz(int r, int k2 /*byte offset in row*/){
    return r * 256 + (k2 ^ ((r & 7) << 4));
}

// ---- fused init: zero bitmap | x->bf16 | weight transposes ----
__global__ __launch_bounds__(256) void k_init(uint4* __restrict__ bits4,
                                              const float* __restrict__ x,
                                              unsigned short* __restrict__ xb,
                                              const float* __restrict__ W0, const float* __restrict__ W1,
                                              const float* __restrict__ W2, const float* __restrict__ Wo,
                                              unsigned short* __restrict__ Wt1a, unsigned short* __restrict__ Wt1b,
                                              unsigned short* __restrict__ Wt2,  unsigned short* __restrict__ Wto,
                                              unsigned short* __restrict__ W0bf){
    int bid = blockIdx.x, t = threadIdx.x;
    if (bid < 512){
        bits4[bid * 256 + t] = (uint4){0u, 0u, 0u, 0u};
        return;
    }
    if (bid < 2560){
        size_t e = (size_t)(bid - 512) * 2048 + t * 8;
        float4 lo = *((const float4*)(x + e));
        float4 hi = *((const float4*)(x + e + 4));
        ushort4 w0, w1;
        w0.x = f2bf(lo.x); w0.y = f2bf(lo.y); w0.z = f2bf(lo.z); w0.w = f2bf(lo.w);
        w1.x = f2bf(hi.x); w1.y = f2bf(hi.y); w1.z = f2bf(hi.z); w1.w = f2bf(hi.w);
        *((ushort4*)(xb + e)) = w0;
        *((ushort4*)(xb + e + 4)) = w1;
        return;
    }
    int idx = (bid - 2560) * 256 + t;   // 0..81919
    int s = idx >> 14;
    int e = idx & 16383;
    int n = e >> 7, k = e & 127;
    float v; unsigned short* dst;
    switch (s){
        case 0:  v = W1[k*128+n];        dst = Wt1a; break;
        case 1:  v = W1[(128+k)*128+n];  dst = Wt1b; break;
        case 2:  v = W2[k*128+n];        dst = Wt2;  break;
        case 3:  v = Wo[k*128+n];        dst = Wto;  break;
        default: v = W0[n*128+k];        dst = W0bf; break;   // natural layout
    }
    dst[n*128+k] = f2bf(v);
}

// ---- stage 128x128 bf16 weight into LDS (swizzled) ----
__device__ __forceinline__ void stage_w(const unsigned short* __restrict__ Wt,
                                        unsigned short* Ws, int t){
    #pragma unroll
    for (int it = 0; it < 8; ++it){
        int g = it * 2048 + t * 8;
        int r = g >> 7, k = g & 127;
        uint4 v = *((const uint4*)(Wt + r * 128 + k));
        *((uint4*)((char*)Ws + swz(r, k * 2))) = v;
    }
}
__device__ __forceinline__ void stage_a_bf16(const unsigned short* __restrict__ src, size_t blockRow,
                                             unsigned short* As, int t){
    #pragma unroll
    for (int it = 0; it < 4; ++it){
        int g = it * 2048 + t * 8;
        int r = g >> 7, k = g & 127;
        uint4 v = *((const uint4*)(src + (blockRow + r) * 128 + k));
        *((uint4*)((char*)As + swz(r, k * 2))) = v;
    }
}
__device__ __forceinline__ void mfma_pass(const unsigned short* As, const unsigned short* Ws,
                                          int wr, int wc, int l15, int lh, f32x4 acc[2][4]){
    #pragma unroll
    for (int ks = 0; ks < 4; ++ks){
        const int kc = ks * 32 + lh * 8;
        short8 af[2], bfv[4];
        #pragma unroll
        for (int m = 0; m < 2; m++){
            int r = wr + m * 16 + l15;
            af[m] = *((const short8*)((const char*)As + swz(r, kc * 2)));
        }
        #pragma unroll
        for (int n = 0; n < 4; n++){
            int r = wc + n * 16 + l15;
            bfv[n] = *((const short8*)((const char*)Ws + swz(r, kc * 2)));
        }
        #pragma unroll
        for (int m = 0; m < 2; m++)
            #pragma unroll
            for (int n = 0; n < 4; n++)
                acc[m][n] = __builtin_amdgcn_mfma_f32_16x16x32_bf16(af[m], bfv[n], acc[m][n], 0, 0, 0);
    }
}

// ---- fused: scatter edges (blocks 0..511) | wprod (block 512) ----
__global__ __launch_bounds__(256) void k_scatter(const int* __restrict__ ei,
                                                 unsigned int* __restrict__ bits,
                                                 const unsigned short* __restrict__ W0bf,
                                                 const unsigned short* __restrict__ Wt1b,
                                                 const float* __restrict__ b0,
                                                 const float* __restrict__ W1,
                                                 unsigned short* __restrict__ Wtu,
                                                 float* __restrict__ c1){
    const int bid = blockIdx.x, t = threadIdx.x;
    if (bid < 512){
        int e = bid * 256 + t;
        int u = ei[e], v = ei[EE + e];
        atomicOr(&bits[u * 128 + (v >> 5)], 1u << (v & 31));
        atomicOr(&bits[v * 128 + (u >> 5)], 1u << (u & 31));
        return;
    }
    // ---- wprod block: Wtu[n][k] = (W0@W1b)[k][n]; c1 = b0@W1b ----
    __shared__ unsigned short As[128*128];
    __shared__ unsigned short Ws[128*128];
    stage_w(W0bf, As, t);
    stage_w(Wt1b, Ws, t);
    __syncthreads();
    const int lane = t & 63, w = t >> 6;
    const int wr = w * 32;
    const int l15 = lane & 15, lh = lane >> 4;
    f32x4 acc[2][8];
    #pragma unroll
    for (int m = 0; m < 2; m++) for (int n = 0; n < 8; n++) acc[m][n] = (f32x4)(0.0f);
    #pragma unroll
    for (int ks = 0; ks < 4; ++ks){
        const int kc = ks * 32 + lh * 8;
        short8 af[2], bfv[8];
        #pragma unroll
        for (int m = 0; m < 2; m++){
            int r = wr + m * 16 + l15;
            af[m] = *((const short8*)((const char*)As + swz(r, kc * 2)));
        }
        #pragma unroll
        for (int n = 0; n < 8; n++){
            int r = n * 16 + l15;
            bfv[n] = *((const short8*)((const char*)Ws + swz(r, kc * 2)));
        }
        #pragma unroll
        for (int m = 0; m < 2; m++)
            #pragma unroll
            for (int n = 0; n < 8; n++)
                acc[m][n] = __builtin_amdgcn_mfma_f32_16x16x32_bf16(af[m], bfv[n], acc[m][n], 0, 0, 0);
    }
    #pragma unroll
    for (int m = 0; m < 2; m++){
        #pragma unroll
        for (int rr = 0; rr < 4; rr++){
            int r = wr + m * 16 + lh * 4 + rr;
            #pragma unroll
            for (int n = 0; n < 8; n++){
                int c = n * 16 + l15;
                Wtu[c * 128 + r] = f2bf(acc[m][n][rr]);
            }
        }
    }
    if (t < 128){
        float s = 0.f;
        #pragma unroll 8
        for (int k = 0; k < 128; k++)
            s += b0[k] * W1[(size_t)(128 + k) * 128 + t];
        c1[t] = s;
    }
}

// ---- compact bitmap row -> padded CSR (uint16 cols, skip diagonal) ----
__global__ __launch_bounds__(128) void k_csr(const unsigned int* __restrict__ bits,
                                             unsigned short* __restrict__ cols, int* __restrict__ deg){
    __shared__ int sc[128];
    int i = blockIdx.x, t = threadIdx.x;
    unsigned int w = bits[i * 128 + t];
    if (t == (i >> 5)) w &= ~(1u << (i & 31));   // zero diagonal
    int c = __popc(w);
    sc[t] = c; __syncthreads();
    int val = c;
    for (int off = 1; off < 128; off <<= 1){
        int add = (t >= off) ? sc[t - off] : 0;
        __syncthreads();
        val += add; sc[t] = val;
        __syncthreads();
    }
    int total = sc[127];
    int pos = val - c;   // exclusive prefix
    unsigned int ww = w;
    while (ww){
        int b = __ffs(ww) - 1;
        ww &= ww - 1;
        if (pos < DEG_CAP) cols[(size_t)i * DEG_CAP + pos] = (unsigned short)(t * 32 + b);
        pos++;
    }
    if (t == 0) deg[i] = total < DEG_CAP ? total : DEG_CAP;
}

__device__ __forceinline__ void acc8u(uint4 u, float* a){
    a[0] += bf2f(u.x & 0xFFFFu); a[1] += bf2f(u.x >> 16);
    a[2] += bf2f(u.y & 0xFFFFu); a[3] += bf2f(u.y >> 16);
    a[4] += bf2f(u.z & 0xFFFFu); a[5] += bf2f(u.z >> 16);
    a[6] += bf2f(u.w & 0xFFFFu); a[7] += bf2f(u.w >> 16);
}

// ---- LDS-resident channel-sliced gather: u = A.xb ----
// bid: s = bid>>5 (slice 0..7), m = bid&31 = b*4+g  -> all 8 slices of (b,g)
// share bid%8 ... m%8 -> same XCD under round-robin (table-line sharing).
// Block: stage slice table (4096 x 16ch = 128 KB) into LDS, then 16 waves x
// 64 nodes: lane-pair per node (2 x 16B = 32B row), 32 nodes/wave-instr,
// private per-lane accumulation (no cross-lane reduction).
__global__ __launch_bounds__(1024) void k_agg(const unsigned short* __restrict__ xb,
                                              const unsigned short* __restrict__ cols,
                                              const int* __restrict__ deg,
                                              unsigned short* __restrict__ agg){
    extern __shared__ unsigned short tab[];   // 4096 * 16 bf16 = 128 KB
    const int t = threadIdx.x;
    const int bid = blockIdx.x;
    const int s = bid >> 5;            // slice
    const int m = bid & 31;
    const int b = m >> 2, g = m & 3;   // batch, node-group

    // stage table: rows j, 16 ch (32 B) each; 2 threads per row
    {
        const int half = t & 1, pr = t >> 1;   // pr 0..511
        const unsigned short* src = xb + (size_t)b * (NN*128) + s * 16 + half * 8;
        #pragma unroll
        for (int it = 0; it < 8; ++it){
            int j = it * 512 + pr;
            uint4 v = *((const uint4*)(src + (size_t)j * 128));
            *((uint4*)(tab + j * 16 + half * 8)) = v;
        }
    }
    __syncthreads();

    const int lane = t & 63, w = t >> 6;   // 16 waves
    const int p = lane >> 1, h = lane & 1; // node-pair index, channel half
    #pragma unroll
    for (int sg = 0; sg < 2; ++sg){
        const int node = g * 1024 + w * 64 + sg * 32 + p;
        const int d = deg[node];
        const unsigned short* cl = cols + (size_t)node * DEG_CAP;
        float a[8];
        #pragma unroll
        for (int q = 0; q < 8; q++) a[q] = 0.f;
        int n = 0;
        for (; n + 3 < d; n += 4){
            int c0 = cl[n], c1 = cl[n+1], c2 = cl[n+2], c3 = cl[n+3];
            uint4 v0 = *((const uint4*)(tab + c0 * 16 + h * 8));
            uint4 v1 = *((const uint4*)(tab + c1 * 16 + h * 8));
            uint4 v2 = *((const uint4*)(tab + c2 * 16 + h * 8));
            uint4 v3 = *((const uint4*)(tab + c3 * 16 + h * 8));
            acc8u(v0, a); acc8u(v1, a); acc8u(v2, a); acc8u(v3, a);
        }
        for (; n < d; ++n){
            uint4 v0 = *((const uint4*)(tab + cl[n] * 16 + h * 8));
            acc8u(v0, a);
        }
        uint4 o;
        o.x = (unsigned)f2bf(a[0]) | ((unsigned)f2bf(a[1]) << 16);
        o.y = (unsigned)f2bf(a[2]) | ((unsigned)f2bf(a[3]) << 16);
        o.z = (unsigned)f2bf(a[4]) | ((unsigned)f2bf(a[5]) << 16);
        o.w = (unsigned)f2bf(a[6]) | ((unsigned)f2bf(a[7]) << 16);
        *((uint4*)(agg + (size_t)b * (NN*128) + (size_t)node * 128 + s * 16 + h * 8)) = o;
    }
}

// ---- fused MLP: out = gelu((xb@W1a + u@Wtu + deg*c1 + b1)@W2 + b2)@Wo + bo + xb ----
__global__ __launch_bounds__(256) void k_mlp(const unsigned short* __restrict__ xb,
                                             const unsigned short* __restrict__ u,
                                             const unsigned short* __restrict__ Wt1a,
                                             const unsigned short* __restrict__ Wtu,
                                             const unsigned short* __restrict__ Wt2,
                                             const unsigned short* __restrict__ Wto,
                                             const float* __restrict__ c1,
                                             const float* __restrict__ b1,
                                             const float* __restrict__ b2,
                                             const float* __restrict__ bo,
                                             const int* __restrict__ deg,
                                             float* __restrict__ out){
    __shared__ unsigned short As[64*128];
    __shared__ unsigned short Ws[128*128];
    const int t = threadIdx.x;
    const size_t blockRow = (size_t)blockIdx.x * 64;
    const int lane = t & 63, w = t >> 6;
    const int wr = (w >> 1) * 32, wc = (w & 1) * 64;
    const int l15 = lane & 15, lh = lane >> 4;

    f32x4 acc[2][4];
    #pragma unroll
    for (int m = 0; m < 2; m++) for (int n = 0; n < 4; n++) acc[m][n] = (f32x4)(0.0f);

    // pass1: xb @ W1a
    stage_a_bf16(xb, blockRow, As, t);
    stage_w(Wt1a, Ws, t);
    __syncthreads();
    mfma_pass(As, Ws, wr, wc, l15, lh, acc);

    // seed acc3 = residual (bf16 x from LDS tile) + bo
    f32x4 acc3[2][4];
    #pragma unroll
    for (int m = 0; m < 2; m++){
        #pragma unroll
        for (int rr = 0; rr < 4; rr++){
            int rl = wr + m * 16 + lh * 4 + rr;
            #pragma unroll
            for (int n = 0; n < 4; n++){
                int col = wc + n * 16 + l15;
                unsigned int us = *((const unsigned short*)((const char*)As + swz(rl, col * 2)));
                acc3[m][n][rr] = bf2f(us) + bo[col];
            }
        }
    }
    __syncthreads();

    // pass2: + u @ Wtu
    stage_a_bf16(u, blockRow, As, t);
    stage_w(Wtu, Ws, t);
    __syncthreads();
    mfma_pass(As, Ws, wr, wc, l15, lh, acc);
    __syncthreads();

    // t1 = acc + b1 + deg*c1 -> As (bf16, swizzled); stage W2
    #pragma unroll
    for (int m = 0; m < 2; m++){
        #pragma unroll
        for (int rr = 0; rr < 4; rr++){
            int rl = wr + m * 16 + lh * 4 + rr;
            int node = (int)((blockRow + rl) & (NN - 1));
            float degf = (float)deg[node];
            #pragma unroll
            for (int n = 0; n < 4; n++){
                int col = wc + n * 16 + l15;
                float v = acc[m][n][rr] + b1[col] + degf * c1[col];
                *((unsigned short*)((char*)As + swz(rl, col * 2))) = f2bf(v);
            }
        }
    }
    stage_w(Wt2, Ws, t);
    __syncthreads();

    // pass3: t1 @ W2
    f32x4 acc2[2][4];
    #pragma unroll
    for (int m = 0; m < 2; m++) for (int n = 0; n < 4; n++) acc2[m][n] = (f32x4)(0.0f);
    mfma_pass(As, Ws, wr, wc, l15, lh, acc2);
    __syncthreads();

    // g = gelu(acc2 + b2) -> As; stage Wo
    #pragma unroll
    for (int m = 0; m < 2; m++){
        #pragma unroll
        for (int rr = 0; rr < 4; rr++){
            int rl = wr + m * 16 + lh * 4 + rr;
            #pragma unroll
            for (int n = 0; n < 4; n++){
                int col = wc + n * 16 + l15;
                float v = acc2[m][n][rr] + b2[col];
                v = 0.5f * v * (1.0f + erff(v * 0.70710678118f));
                *((unsigned short*)((char*)As + swz(rl, col * 2))) = f2bf(v);
            }
        }
    }
    stage_w(Wto, Ws, t);
    __syncthreads();

    // pass4: acc3 += g @ Wo
    mfma_pass(As, Ws, wr, wc, l15, lh, acc3);

    #pragma unroll
    for (int m = 0; m < 2; m++){
        #pragma unroll
        for (int rr = 0; rr < 4; rr++){
            size_t row = blockRow + wr + m * 16 + lh * 4 + rr;
            #pragma unroll
            for (int n = 0; n < 4; n++){
                int col = wc + n * 16 + l15;
                out[row * 128 + col] = acc3[m][n][rr];
            }
        }
    }
}

extern "C" void kernel_launch(void* const* d_in, const int* in_sizes, int n_in,
                              void* d_out, int out_size, void* d_ws, size_t ws_size,
                              hipStream_t stream) {
    const float* x  = (const float*)d_in[0];
    const int*   ei = (const int*)d_in[1];
    const float* W0 = (const float*)d_in[2];
    const float* b0 = (const float*)d_in[3];
    const float* W1 = (const float*)d_in[4];
    const float* b1 = (const float*)d_in[5];
    const float* W2 = (const float*)d_in[6];
    const float* b2 = (const float*)d_in[7];
    const float* Wo = (const float*)d_in[8];
    const float* bo = (const float*)d_in[9];
    float* out = (float*)d_out;

    char* ws = (char*)d_ws;
    unsigned int* bits    = (unsigned int*)(ws + 0);                  // 2 MB
    int*   deg            = (int*)(ws + 2097152);                     // 16 KB
    unsigned short* cols  = (unsigned short*)(ws + 2113536);          // 1 MB (uint16, DEG_CAP=128)
    unsigned short* xb    = (unsigned short*)(ws + 3162112);          // 8 MB
    unsigned short* ubuf  = (unsigned short*)(ws + 11550720);         // 8 MB
    unsigned short* Wt1a  = (unsigned short*)(ws + 19939328);
    unsigned short* Wt1b  = (unsigned short*)(ws + 19939328 + 32768);
    unsigned short* Wt2   = (unsigned short*)(ws + 19939328 + 65536);
    unsigned short* Wto   = (unsigned short*)(ws + 19939328 + 98304);
    unsigned short* W0bf  = (unsigned short*)(ws + 19939328 + 131072);
    unsigned short* Wtu   = (unsigned short*)(ws + 19939328 + 163840);
    float* c1             = (float*)(ws + 19939328 + 196608);

    // allow 128 KB dynamic LDS for k_agg (idempotent, capture-safe)
    hipFuncSetAttribute((const void*)k_agg, hipFuncAttributeMaxDynamicSharedMemorySize, 131072);

    k_init<<<2880, 256, 0, stream>>>((uint4*)bits, x, xb, W0, W1, W2, Wo,
                                     Wt1a, Wt1b, Wt2, Wto, W0bf);
    k_scatter<<<513, 256, 0, stream>>>(ei, bits, W0bf, Wt1b, b0, W1, Wtu, c1);
    k_csr<<<NN, 128, 0, stream>>>(bits, cols, deg);
    k_agg<<<256, 1024, 131072, stream>>>(xb, cols, deg, ubuf);
    k_mlp<<<M_ROWS / 64, 256, 0, stream>>>(xb, ubuf, Wt1a, Wtu, Wt2, Wto,
                                           c1, b1, b2, bo, deg, out);
}

// Round 16
// 74.475 us; speedup vs baseline: 1.0877x; 1.0877x over previous
//
#include <hip/hip_runtime.h>
#include <hip/hip_bf16.h>
#include <math.h>

#define NN 4096
#define BB 8
#define CC 128
#define EE 131072
#define M_ROWS (BB*NN)      // 32768
#define DEG_CAP 512

typedef __attribute__((ext_vector_type(8))) short short8;
typedef __attribute__((ext_vector_type(4))) float f32x4;

__device__ __forceinline__ float bf2f(unsigned int u){
    union { unsigned int i; float f; } v; v.i = u << 16; return v.f;
}
__device__ __forceinline__ unsigned short f2bf(float f){
    union { float f; unsigned int i; } v; v.f = f;
    unsigned int u = v.i;
    unsigned int r = u + 0x7FFFu + ((u >> 16) & 1u);
    return (unsigned short)(r >> 16);
}

// swizzled byte offset for element (row r, k) in a [rows][128] bf16 LDS tile (256B rows)
__device__ __forceinline__ int swz(int r, int k2 /*byte offset in row*/){
    return r * 256 + (k2 ^ ((r & 7) << 4));
}

// ---- fused init: zero bitmap | x->bf16 | weight transposes ----
__global__ __launch_bounds__(256) void k_init(uint4* __restrict__ bits4,
                                              const float* __restrict__ x,
                                              unsigned short* __restrict__ xb,
                                              const float* __restrict__ W0, const float* __restrict__ W1,
                                              const float* __restrict__ W2, const float* __restrict__ Wo,
                                              unsigned short* __restrict__ Wt1a, unsigned short* __restrict__ Wt1b,
                                              unsigned short* __restrict__ Wt2,  unsigned short* __restrict__ Wto,
                                              unsigned short* __restrict__ W0bf){
    int bid = blockIdx.x, t = threadIdx.x;
    if (bid < 512){
        bits4[bid * 256 + t] = (uint4){0u, 0u, 0u, 0u};
        return;
    }
    if (bid < 2560){
        size_t e = (size_t)(bid - 512) * 2048 + t * 8;
        float4 lo = *((const float4*)(x + e));
        float4 hi = *((const float4*)(x + e + 4));
        ushort4 w0, w1;
        w0.x = f2bf(lo.x); w0.y = f2bf(lo.y); w0.z = f2bf(lo.z); w0.w = f2bf(lo.w);
        w1.x = f2bf(hi.x); w1.y = f2bf(hi.y); w1.z = f2bf(hi.z); w1.w = f2bf(hi.w);
        *((ushort4*)(xb + e)) = w0;
        *((ushort4*)(xb + e + 4)) = w1;
        return;
    }
    int idx = (bid - 2560) * 256 + t;   // 0..81919
    int s = idx >> 14;
    int e = idx & 16383;
    int n = e >> 7, k = e & 127;
    float v; unsigned short* dst;
    switch (s){
        case 0:  v = W1[k*128+n];        dst = Wt1a; break;
        case 1:  v = W1[(128+k)*128+n];  dst = Wt1b; break;
        case 2:  v = W2[k*128+n];        dst = Wt2;  break;
        case 3:  v = Wo[k*128+n];        dst = Wto;  break;
        default: v = W0[n*128+k];        dst = W0bf; break;   // natural layout
    }
    dst[n*128+k] = f2bf(v);
}

// ---- stage 128x128 bf16 weight into LDS (swizzled) ----
__device__ __forceinline__ void stage_w(const unsigned short* __restrict__ Wt,
                                        unsigned short* Ws, int t){
    #pragma unroll
    for (int it = 0; it < 8; ++it){
        int g = it * 2048 + t * 8;
        int r = g >> 7, k = g & 127;
        uint4 v = *((const uint4*)(Wt + r * 128 + k));
        *((uint4*)((char*)Ws + swz(r, k * 2))) = v;
    }
}
__device__ __forceinline__ void stage_a_bf16(const unsigned short* __restrict__ src, size_t blockRow,
                                             unsigned short* As, int t){
    #pragma unroll
    for (int it = 0; it < 4; ++it){
        int g = it * 2048 + t * 8;
        int r = g >> 7, k = g & 127;
        uint4 v = *((const uint4*)(src + (blockRow + r) * 128 + k));
        *((uint4*)((char*)As + swz(r, k * 2))) = v;
    }
}
__device__ __forceinline__ void mfma_pass(const unsigned short* As, const unsigned short* Ws,
                                          int wr, int wc, int l15, int lh, f32x4 acc[2][4]){
    #pragma unroll
    for (int ks = 0; ks < 4; ++ks){
        const int kc = ks * 32 + lh * 8;
        short8 af[2], bfv[4];
        #pragma unroll
        for (int m = 0; m < 2; m++){
            int r = wr + m * 16 + l15;
            af[m] = *((const short8*)((const char*)As + swz(r, kc * 2)));
        }
        #pragma unroll
        for (int n = 0; n < 4; n++){
            int r = wc + n * 16 + l15;
            bfv[n] = *((const short8*)((const char*)Ws + swz(r, kc * 2)));
        }
        #pragma unroll
        for (int m = 0; m < 2; m++)
            #pragma unroll
            for (int n = 0; n < 4; n++)
                acc[m][n] = __builtin_amdgcn_mfma_f32_16x16x32_bf16(af[m], bfv[n], acc[m][n], 0, 0, 0);
    }
}

// ---- fused: scatter edges (blocks 0..511) | wprod (block 512) ----
__global__ __launch_bounds__(256) void k_scatter(const int* __restrict__ ei,
                                                 unsigned int* __restrict__ bits,
                                                 const unsigned short* __restrict__ W0bf,
                                                 const unsigned short* __restrict__ Wt1b,
                                                 const float* __restrict__ b0,
                                                 const float* __restrict__ W1,
                                                 unsigned short* __restrict__ Wtu,
                                                 float* __restrict__ c1){
    const int bid = blockIdx.x, t = threadIdx.x;
    if (bid < 512){
        int e = bid * 256 + t;
        int u = ei[e], v = ei[EE + e];
        atomicOr(&bits[u * 128 + (v >> 5)], 1u << (v & 31));
        atomicOr(&bits[v * 128 + (u >> 5)], 1u << (u & 31));
        return;
    }
    // ---- wprod block: Wtu[n][k] = (W0@W1b)[k][n]; c1 = b0@W1b ----
    __shared__ unsigned short As[128*128];
    __shared__ unsigned short Ws[128*128];
    stage_w(W0bf, As, t);
    stage_w(Wt1b, Ws, t);
    __syncthreads();
    const int lane = t & 63, w = t >> 6;
    const int wr = w * 32;
    const int l15 = lane & 15, lh = lane >> 4;
    f32x4 acc[2][8];
    #pragma unroll
    for (int m = 0; m < 2; m++) for (int n = 0; n < 8; n++) acc[m][n] = (f32x4)(0.0f);
    #pragma unroll
    for (int ks = 0; ks < 4; ++ks){
        const int kc = ks * 32 + lh * 8;
        short8 af[2], bfv[8];
        #pragma unroll
        for (int m = 0; m < 2; m++){
            int r = wr + m * 16 + l15;
            af[m] = *((const short8*)((const char*)As + swz(r, kc * 2)));
        }
        #pragma unroll
        for (int n = 0; n < 8; n++){
            int r = n * 16 + l15;
            bfv[n] = *((const short8*)((const char*)Ws + swz(r, kc * 2)));
        }
        #pragma unroll
        for (int m = 0; m < 2; m++)
            #pragma unroll
            for (int n = 0; n < 8; n++)
                acc[m][n] = __builtin_amdgcn_mfma_f32_16x16x32_bf16(af[m], bfv[n], acc[m][n], 0, 0, 0);
    }
    #pragma unroll
    for (int m = 0; m < 2; m++){
        #pragma unroll
        for (int rr = 0; rr < 4; rr++){
            int r = wr + m * 16 + lh * 4 + rr;
            #pragma unroll
            for (int n = 0; n < 8; n++){
                int c = n * 16 + l15;
                Wtu[c * 128 + r] = f2bf(acc[m][n][rr]);
            }
        }
    }
    if (t < 128){
        float s = 0.f;
        #pragma unroll 8
        for (int k = 0; k < 128; k++)
            s += b0[k] * W1[(size_t)(128 + k) * 128 + t];
        c1[t] = s;
    }
}

__device__ __forceinline__ void acc8u(uint4 u, float* a){
    a[0] += bf2f(u.x & 0xFFFFu); a[1] += bf2f(u.x >> 16);
    a[2] += bf2f(u.y & 0xFFFFu); a[3] += bf2f(u.y >> 16);
    a[4] += bf2f(u.z & 0xFFFFu); a[5] += bf2f(u.z >> 16);
    a[6] += bf2f(u.w & 0xFFFFu); a[7] += bf2f(u.w >> 16);
}

// ---- sparse aggregation with inline bitmap->CSR expansion ----
// One wave per (b,i). Expansion: uint2 bitmap words per lane, popc + shfl prefix
// scan -> scol LDS. Gather: sub=lane>>4 neighbor stream, li=lane&15 channels,
// 4 uint4 loads in flight per wave iteration (16 rows/iter).
__global__ __launch_bounds__(256) void k_agg(const unsigned short* __restrict__ h,
                                             const unsigned int* __restrict__ bits,
                                             int* __restrict__ deg,
                                             unsigned short* __restrict__ agg){
    __shared__ unsigned short scol[4][DEG_CAP];
    const int t = threadIdx.x;
    const int w = t >> 6, lane = t & 63;
    const int b = blockIdx.x & 7;                  // XCD-aligned batch
    const int i = ((blockIdx.x >> 3) << 2) + w;    // node

    // inline CSR expansion for node i
    uint2 wv = *((const uint2*)(bits + i * 128 + lane * 2));
    unsigned int w0 = wv.x, w1 = wv.y;
    int dw = i >> 5;                               // diagonal word index
    if (dw == lane * 2)          w0 &= ~(1u << (i & 31));
    else if (dw == lane * 2 + 1) w1 &= ~(1u << (i & 31));
    int c = __popc(w0) + __popc(w1);
    int incl = c;
    #pragma unroll
    for (int off = 1; off < 64; off <<= 1){
        int nb = __shfl_up(incl, off);
        if (lane >= off) incl += nb;
    }
    int total = __shfl(incl, 63);
    int pos = incl - c;
    int base = lane * 64;
    unsigned int ww = w0;
    while (ww){
        int bit = __ffs(ww) - 1; ww &= ww - 1;
        if (pos < DEG_CAP) scol[w][pos] = (unsigned short)(base + bit);
        pos++;
    }
    ww = w1; base += 32;
    while (ww){
        int bit = __ffs(ww) - 1; ww &= ww - 1;
        if (pos < DEG_CAP) scol[w][pos] = (unsigned short)(base + bit);
        pos++;
    }
    const int d = total < DEG_CAP ? total : DEG_CAP;
    if (b == 0 && lane == 0) deg[i] = d;
    // same-wave LDS RAW: DS pipe ordered per wave (lgkmcnt)

    const int sub = lane >> 4, li = lane & 15;
    const unsigned short* hb = h + (size_t)b * (NN*128) + li * 8;
    float a[8];
    #pragma unroll
    for (int q = 0; q < 8; q++) a[q] = 0.f;

    int n = sub;
    for (; n + 12 < d; n += 16){
        int j0 = scol[w][n], j1 = scol[w][n+4], j2 = scol[w][n+8], j3 = scol[w][n+12];
        uint4 u0 = *((const uint4*)(hb + ((size_t)j0 << 7)));
        uint4 u1 = *((const uint4*)(hb + ((size_t)j1 << 7)));
        uint4 u2 = *((const uint4*)(hb + ((size_t)j2 << 7)));
        uint4 u3 = *((const uint4*)(hb + ((size_t)j3 << 7)));
        acc8u(u0, a); acc8u(u1, a); acc8u(u2, a); acc8u(u3, a);
    }
    for (; n < d; n += 4){
        uint4 u0 = *((const uint4*)(hb + ((size_t)scol[w][n] << 7)));
        acc8u(u0, a);
    }
    #pragma unroll
    for (int q = 0; q < 8; q++){
        a[q] += __shfl_xor(a[q], 16);
        a[q] += __shfl_xor(a[q], 32);
    }
    if (sub == 0){
        uint4 o;
        o.x = (unsigned)f2bf(a[0]) | ((unsigned)f2bf(a[1]) << 16);
        o.y = (unsigned)f2bf(a[2]) | ((unsigned)f2bf(a[3]) << 16);
        o.z = (unsigned)f2bf(a[4]) | ((unsigned)f2bf(a[5]) << 16);
        o.w = (unsigned)f2bf(a[6]) | ((unsigned)f2bf(a[7]) << 16);
        *((uint4*)(agg + (size_t)b * (NN*128) + ((size_t)i << 7) + li * 8)) = o;
    }
}

// ---- fused MLP: out = gelu((xb@W1a + u@Wtu + deg*c1 + b1)@W2 + b2)@Wo + bo + xb ----
__global__ __launch_bounds__(256) void k_mlp(const unsigned short* __restrict__ xb,
                                             const unsigned short* __restrict__ u,
                                             const unsigned short* __restrict__ Wt1a,
                                             const unsigned short* __restrict__ Wtu,
                                             const unsigned short* __restrict__ Wt2,
                                             const unsigned short* __restrict__ Wto,
                                             const float* __restrict__ c1,
                                             const float* __restrict__ b1,
                                             const float* __restrict__ b2,
                                             const float* __restrict__ bo,
                                             const int* __restrict__ deg,
                                             float* __restrict__ out){
    __shared__ unsigned short As[64*128];
    __shared__ unsigned short Ws[128*128];
    const int t = threadIdx.x;
    const size_t blockRow = (size_t)blockIdx.x * 64;
    const int lane = t & 63, w = t >> 6;
    const int wr = (w >> 1) * 32, wc = (w & 1) * 64;
    const int l15 = lane & 15, lh = lane >> 4;

    f32x4 acc[2][4];
    #pragma unroll
    for (int m = 0; m < 2; m++) for (int n = 0; n < 4; n++) acc[m][n] = (f32x4)(0.0f);

    // pass1: xb @ W1a
    stage_a_bf16(xb, blockRow, As, t);
    stage_w(Wt1a, Ws, t);
    __syncthreads();
    mfma_pass(As, Ws, wr, wc, l15, lh, acc);

    // seed acc3 = residual (bf16 x from LDS tile) + bo
    f32x4 acc3[2][4];
    #pragma unroll
    for (int m = 0; m < 2; m++){
        #pragma unroll
        for (int rr = 0; rr < 4; rr++){
            int rl = wr + m * 16 + lh * 4 + rr;
            #pragma unroll
            for (int n = 0; n < 4; n++){
                int col = wc + n * 16 + l15;
                unsigned int us = *((const unsigned short*)((const char*)As + swz(rl, col * 2)));
                acc3[m][n][rr] = bf2f(us) + bo[col];
            }
        }
    }
    __syncthreads();

    // pass2: + u @ Wtu
    stage_a_bf16(u, blockRow, As, t);
    stage_w(Wtu, Ws, t);
    __syncthreads();
    mfma_pass(As, Ws, wr, wc, l15, lh, acc);
    __syncthreads();

    // t1 = acc + b1 + deg*c1 -> As (bf16, swizzled); stage W2
    #pragma unroll
    for (int m = 0; m < 2; m++){
        #pragma unroll
        for (int rr = 0; rr < 4; rr++){
            int rl = wr + m * 16 + lh * 4 + rr;
            int node = (int)((blockRow + rl) & (NN - 1));
            float degf = (float)deg[node];
            #pragma unroll
            for (int n = 0; n < 4; n++){
                int col = wc + n * 16 + l15;
                float v = acc[m][n][rr] + b1[col] + degf * c1[col];
                *((unsigned short*)((char*)As + swz(rl, col * 2))) = f2bf(v);
            }
        }
    }
    stage_w(Wt2, Ws, t);
    __syncthreads();

    // pass3: t1 @ W2
    f32x4 acc2[2][4];
    #pragma unroll
    for (int m = 0; m < 2; m++) for (int n = 0; n < 4; n++) acc2[m][n] = (f32x4)(0.0f);
    mfma_pass(As, Ws, wr, wc, l15, lh, acc2);
    __syncthreads();

    // g = gelu(acc2 + b2) -> As; stage Wo
    #pragma unroll
    for (int m = 0; m < 2; m++){
        #pragma unroll
        for (int rr = 0; rr < 4; rr++){
            int rl = wr + m * 16 + lh * 4 + rr;
            #pragma unroll
            for (int n = 0; n < 4; n++){
                int col = wc + n * 16 + l15;
                float v = acc2[m][n][rr] + b2[col];
                v = 0.5f * v * (1.0f + erff(v * 0.70710678118f));
                *((unsigned short*)((char*)As + swz(rl, col * 2))) = f2bf(v);
            }
        }
    }
    stage_w(Wto, Ws, t);
    __syncthreads();

    // pass4: acc3 += g @ Wo
    mfma_pass(As, Ws, wr, wc, l15, lh, acc3);

    #pragma unroll
    for (int m = 0; m < 2; m++){
        #pragma unroll
        for (int rr = 0; rr < 4; rr++){
            size_t row = blockRow + wr + m * 16 + lh * 4 + rr;
            #pragma unroll
            for (int n = 0; n < 4; n++){
                int col = wc + n * 16 + l15;
                out[row * 128 + col] = acc3[m][n][rr];
            }
        }
    }
}

extern "C" void kernel_launch(void* const* d_in, const int* in_sizes, int n_in,
                              void* d_out, int out_size, void* d_ws, size_t ws_size,
                              hipStream_t stream) {
    const float* x  = (const float*)d_in[0];
    const int*   ei = (const int*)d_in[1];
    const float* W0 = (const float*)d_in[2];
    const float* b0 = (const float*)d_in[3];
    const float* W1 = (const float*)d_in[4];
    const float* b1 = (const float*)d_in[5];
    const float* W2 = (const float*)d_in[6];
    const float* b2 = (const float*)d_in[7];
    const float* Wo = (const float*)d_in[8];
    const float* bo = (const float*)d_in[9];
    float* out = (float*)d_out;

    char* ws = (char*)d_ws;
    unsigned int* bits    = (unsigned int*)(ws + 0);                  // 2 MB
    int*   deg            = (int*)(ws + 2097152);                     // 16 KB
    unsigned short* xb    = (unsigned short*)(ws + 2113536);          // 8 MB
    unsigned short* ubuf  = (unsigned short*)(ws + 10502144);         // 8 MB
    unsigned short* Wt1a  = (unsigned short*)(ws + 18890752);
    unsigned short* Wt1b  = (unsigned short*)(ws + 18890752 + 32768);
    unsigned short* Wt2   = (unsigned short*)(ws + 18890752 + 65536);
    unsigned short* Wto   = (unsigned short*)(ws + 18890752 + 98304);
    unsigned short* W0bf  = (unsigned short*)(ws + 18890752 + 131072);
    unsigned short* Wtu   = (unsigned short*)(ws + 18890752 + 163840);
    float* c1             = (float*)(ws + 18890752 + 196608);

    k_init<<<2880, 256, 0, stream>>>((uint4*)bits, x, xb, W0, W1, W2, Wo,
                                     Wt1a, Wt1b, Wt2, Wto, W0bf);
    k_scatter<<<513, 256, 0, stream>>>(ei, bits, W0bf, Wt1b, b0, W1, Wtu, c1);
    k_agg<<<BB * (NN / 4), 256, 0, stream>>>(xb, bits, deg, ubuf);
    k_mlp<<<M_ROWS / 64, 256, 0, stream>>>(xb, ubuf, Wt1a, Wtu, Wt2, Wto,
                                           c1, b1, b2, bo, deg, out);
}